// Round 8
// baseline (65.557 us; speedup 1.0000x reference)
//
#include <hip/hip_runtime.h>
#include <math.h>

#define NN 2048
#define CC 64
#define SS 128
#define KK 8
#define TCAP 128   /* candidate cap per 2x32 tile; E[cn]~22, P(overflow)~0 */
#define FP 68      /* sF slot stride (dwords): 272B, 16B-aligned; banks (4s+c)%32 */

// RADIUS_NDC = 1.5/128*2 = 3/128 (exact dyadic); R2 = 9/16384 (exact dyadic)
#define R2f    0.00054931640625f
#define RNDCf  0.0234375f

// Fused raster+composite, ONE block per 2x32-pixel tile, all 64 channels.
// Grid = 512: blk = b(1)|ty(6)|tx(2).
//   A: bbox-bin points into LDS (atomic append, unordered)
//   S: rank-sort candidates by u64 (z_bits, idx) key (unique -> total order ==
//      jax.lax.top_k smallest-z / lowest-index-tie order)
//   B (wave 0): per-pixel online front-to-back pass — first 8 strict d2<R2
//      hits in ascending-key order ARE the top-8; transmittance online.
//   G (waves 1-3, concurrent with B): gather candidate feature rows (64 ch)
//      into LDS.
//   C: weighted accumulate — 8 x ds_read_b64 (w,slot) + 32 x ds_read_b128
//      (features, 16 ch/thread); coalesced 128B-segment stores.
__global__ __launch_bounds__(256, 2) void raster_fused_kernel(
    const float* __restrict__ pts3D,  // [B, N, 3]
    const float* __restrict__ src,    // [B, C, N]
    float* __restrict__ out)          // [B, C, S, S]
{
    __shared__ float scx[TCAP], scy[TCAP];
    __shared__ unsigned long long skey[TCAP];
    __shared__ float2 ssxy[TCAP];          // sorted (x,y)
    __shared__ int   sid[TCAP];            // sorted slot -> global point idx
    __shared__ int   scount;
    __shared__ float2 sWS[KK * 64];        // (w, slot bits) per (k, pixel)
    __shared__ alignas(16) float sF[TCAP * FP];  // candidate features, 64 ch

    const int tid = threadIdx.x;
    const int blk = blockIdx.x;            // 512
    const int X0  = (blk & 3) * 32;
    const int Y0  = ((blk >> 2) & 63) * 2;
    const int b   = blk >> 8;

    if (tid == 0) scount = 0;
    __syncthreads();

    // ---- Phase A: bin points whose 1.5px disk can touch this tile ----
    // pixel centers p(i) = 1 - (2i+1)/128 (exact dyadic), decreasing in i.
    const float cxc = 1.0f - (2.0f * (float)X0 + 32.0f) / 128.0f;
    const float cyc_ = 1.0f - (2.0f * (float)Y0 + 2.0f) / 128.0f;
    const float rx = 31.0f / 128.0f + RNDCf + 1e-6f;  // strict d2<R2 authoritative
    const float ry = 1.0f / 128.0f + RNDCf + 1e-6f;

    const float* P = pts3D + (size_t)b * NN * 3;
#pragma unroll
    for (int j = 0; j < NN / 256; ++j) {
        int n = tid + j * 256;
        float x = -P[n * 3 + 0], y = -P[n * 3 + 1], z = P[n * 3 + 2];
        if (z > 0.0f && fabsf(x - cxc) <= rx && fabsf(y - cyc_) <= ry) {
            int slot = atomicAdd(&scount, 1);
            if (slot < TCAP) {
                scx[slot] = x;
                scy[slot] = y;
                skey[slot] = ((unsigned long long)__float_as_uint(z) << 32) | (unsigned)n;
            }
        }
    }
    __syncthreads();
    const int cn = min(scount, TCAP);

    // ---- cn==0: block-uniform early out (never multiply w=0 by stale LDS) ----
    if (cn == 0) {
        const int px = tid & 63, cg = tid >> 6;
        const int col = px & 31, r = px >> 5;
        float* O = out + (size_t)b * CC * (SS * SS) + (size_t)(Y0 + r) * SS + (X0 + col);
#pragma unroll
        for (int cc = 0; cc < 16; ++cc)
            O[(size_t)(cg * 16 + cc) * (SS * SS)] = 0.0f;
        return;
    }

    // ---- Phase S: rank-sort by key ascending (keys unique -> bijective) ----
    if (tid < cn) {
        unsigned long long mykey = skey[tid];
        int rank = 0;
        for (int j = 0; j < cn; ++j)           // wave-uniform j -> LDS broadcast
            rank += (skey[j] < mykey) ? 1 : 0;
        ssxy[rank] = make_float2(scx[tid], scy[tid]);
        sid[rank]  = (int)(unsigned)(mykey & 0xffffffffu);
    }
    __syncthreads();

    if (tid < 64) {
        // ---- Phase B (wave 0): online front-to-back composite weights ----
        const int col = tid & 31, r = tid >> 5;
        const float pcx = 1.0f - (2.0f * (float)(X0 + col) + 1.0f) / 128.0f;
        const float pcy = 1.0f - (2.0f * (float)(Y0 + r) + 1.0f) / 128.0f;
        float T = 1.0f;
        int cnt = 0;
        for (int i = 0; i < cn; ++i) {
            float2 pxy = ssxy[i];              // one b64 broadcast per candidate
            float dx = pcx - pxy.x;
            float dy = pcy - pxy.y;
            float d2 = dy * dy + dx * dx;      // ref op order (dy2+dx2)
            if (d2 < R2f && cnt < KK) {
                float dn = d2 / R2f;           // ref: dist_sel / RADIUS_NDC**2
                dn = fminf(fmaxf(dn, 0.001f), 1.0f);
                float a = 1.0f - sqrtf(dn);    // tau = 1
                sWS[cnt * 64 + tid] = make_float2(a * T, __int_as_float(i));
                T *= (1.0f - a);
                ++cnt;
            }
        }
        for (; cnt < KK; ++cnt)                // tail: w=0, slot=0 (sF row 0 valid)
            sWS[cnt * 64 + tid] = make_float2(0.0f, __int_as_float(0));
    } else {
        // ---- Phase G (waves 1-3): gather candidate feature rows into LDS ----
        const int lc = tid & 63;               // channel 0..63
        const float* F = src + ((size_t)b * CC + lc) * NN;
        for (int s = (tid - 64) >> 6; s < cn; s += 3)
            sF[s * FP + lc] = F[sid[s]];       // banks lc%32: 2-way free
    }
    __syncthreads();

    // ---- Phase C: weighted accumulate from LDS + coalesced store ----
    const int px = tid & 63;
    const int cg = tid >> 6;                   // 0..3 -> 16 channels each
    float w[KK]; int sl[KK];
#pragma unroll
    for (int k = 0; k < KK; ++k) {
        float2 ws = sWS[k * 64 + px];          // ds_read_b64, stride-1 lanes
        w[k]  = ws.x;
        sl[k] = __float_as_int(ws.y);
    }
    const int col = px & 31, r = px >> 5;
    float* O = out + (size_t)b * CC * (SS * SS) + (size_t)(Y0 + r) * SS + (X0 + col);
#pragma unroll
    for (int g = 0; g < 4; ++g) {              // 4 x float4 channel groups
        float4 acc = make_float4(0.0f, 0.0f, 0.0f, 0.0f);
#pragma unroll
        for (int k = 0; k < KK; ++k) {         // b128; same-slot lanes broadcast
            const float4 f = *reinterpret_cast<const float4*>(
                &sF[sl[k] * FP + cg * 16 + g * 4]);
            acc.x += w[k] * f.x;
            acc.y += w[k] * f.y;
            acc.z += w[k] * f.z;
            acc.w += w[k] * f.w;
        }
        const int c0 = cg * 16 + g * 4;
        O[(size_t)(c0 + 0) * (SS * SS)] = acc.x;   // 2 rows x 32 px = 128B segs
        O[(size_t)(c0 + 1) * (SS * SS)] = acc.y;
        O[(size_t)(c0 + 2) * (SS * SS)] = acc.z;
        O[(size_t)(c0 + 3) * (SS * SS)] = acc.w;
    }
}

extern "C" void kernel_launch(void* const* d_in, const int* in_sizes, int n_in,
                              void* d_out, int out_size, void* d_ws, size_t ws_size,
                              hipStream_t stream) {
    const float* pts3D = (const float*)d_in[0]; // [2,2048,3]
    const float* src   = (const float*)d_in[1]; // [2,64,2048]
    float* out = (float*)d_out;                 // [2,64,128,128]
    (void)in_sizes; (void)n_in; (void)out_size; (void)d_ws; (void)ws_size;

    raster_fused_kernel<<<dim3(512), dim3(256), 0, stream>>>(pts3D, src, out);
}